// Round 1
// baseline (682.872 us; speedup 1.0000x reference)
//
#include <hip/hip_runtime.h>

// Problem constants
#define BATCH 8
#define SEQ   256
#define VOC   50257
#define DIM   128
#define NH    256
#define NROWS 2048            // SEQ*BATCH
#define LOGITS_ELEMS 102926336ULL  // 8*256*50257

constexpr float PHI_F   = 1.61803398874989485f;
constexpr float SCALE_F = (float)(4096.0 / 6.283185307179586);   // RES/(2*pi)
constexpr float STEP_F  = (float)(6.283185307179586 / 4096.0);   // 2*pi/RES

__device__ __forceinline__ unsigned short f2bf(float f) {
    unsigned int u = __float_as_uint(f);
    u = (u + 0x7fffu + ((u >> 16) & 1u)) >> 16;   // RNE
    return (unsigned short)u;
}

// ---------------------------------------------------------------------------
// prep: [0,6283)   out_w fp32 -> bf16
//       [6283,7051) transpose layer weights: wt[i][d][n], wrt[i][n][d], wit[i][n][d]
//       [7051,8075) gather emb -> w_arr/b_arr laid out [t*8+b][d]
// ---------------------------------------------------------------------------
__global__ void prep_kernel(const float* __restrict__ emb,
                            const int*   __restrict__ ids,
                            const float* __restrict__ W,
                            const float* __restrict__ Wr,
                            const float* __restrict__ Wi,
                            const float* __restrict__ outw,
                            unsigned short* __restrict__ outw_bf,
                            float* __restrict__ wt,
                            float* __restrict__ wrt,
                            float* __restrict__ wit,
                            float* __restrict__ w_arr,
                            float* __restrict__ b_arr) {
    int bid = blockIdx.x;
    int tid = threadIdx.x;
    if (bid < 6283) {
        int i4 = bid * 256 + tid;
        if (i4 < (VOC * DIM) / 4) {
            float4 v = ((const float4*)outw)[i4];
            unsigned int lo = ((unsigned)f2bf(v.y) << 16) | f2bf(v.x);
            unsigned int hi = ((unsigned)f2bf(v.w) << 16) | f2bf(v.z);
            ((uint2*)outw_bf)[i4] = make_uint2(lo, hi);
        }
    } else if (bid < 7051) {
        int e = (bid - 6283) * 256 + tid;        // < 196608 exactly
        int tns = e >> 16;                        // 0:W 1:Wr 2:Wi
        int r = e & 65535;
        int i = r >> 15, rem = r & 32767;
        if (tns == 0) {
            int d = rem >> 8, n = rem & 255;
            wt[r] = W[(i * 256 + n) * 128 + d];
        } else if (tns == 1) {
            int n = rem >> 7, d = rem & 127;
            wrt[r] = Wr[(i * 128 + d) * 256 + n];
        } else {
            int n = rem >> 7, d = rem & 127;
            wit[r] = Wi[(i * 128 + d) * 256 + n];
        }
    } else {
        int e = (bid - 7051) * 256 + tid;        // < 262144 exactly
        int row = e >> 7, d = e & 127;
        int t = row >> 3, b = row & 7;
        int id = ids[b * 256 + t];
        w_arr[e] = emb[id * 256 + d];
        b_arr[e] = emb[id * 256 + 128 + d];
    }
}

// ---------------------------------------------------------------------------
// recurrence: 8 blocks (one per batch) x 128 threads (one per d)
// ---------------------------------------------------------------------------
__global__ void recur_kernel(const float* __restrict__ w_arr,
                             const float* __restrict__ b_arr,
                             float* __restrict__ X0,
                             float* __restrict__ out) {
    int b = blockIdx.x, d = threadIdx.x;
    int base = b * 128 + d;
    float hr = 0.0f, hi = 0.0f;
    for (int t = 0; t < 256; ++t) {
        int off = t * 1024 + base;
        float w  = w_arr[off];
        float bv = b_arr[off];
        float tphi = (float)t * PHI_F;
        float th = (hr + hi) / (1.0f + fabsf(w)) + bv + tphi;
        int idx = ((int)rintf(th * SCALE_F)) & 4095;
        float ang = (float)idx * STEP_F;
        hi = __sinf(ang);
        hr = __cosf(ang);
        X0[off] = hr + hi;
    }
    out[LOGITS_ELEMS + base] = hr;
    out[LOGITS_ELEMS + 1024 + base] = hi;
}

// ---------------------------------------------------------------------------
// layers: 256 blocks (one per t) x 256 threads; 8 rows (all b) per block
// ---------------------------------------------------------------------------
__global__ void layers_kernel(const float* __restrict__ X0,
                              const float* __restrict__ wt,
                              const float* __restrict__ wrt,
                              const float* __restrict__ wit,
                              const float* __restrict__ lb,
                              unsigned short* __restrict__ X2bf) {
    __shared__ float xs[1024];     // [r][d]
    __shared__ float csh[2048];    // [r][n]
    __shared__ float snh[2048];
    __shared__ float part[1024];
    int tid = threadIdx.x, t = blockIdx.x;
    float tphi = (float)t * PHI_F;
    ((float4*)xs)[tid] = ((const float4*)(X0 + t * 1024))[tid];
    __syncthreads();
    for (int i = 0; i < 2; ++i) {
        // phase 1: th[r][n] = x[r] . W[n] + b[n] + tphi ; sn/cs lookup
        const float* wti = wt + i * 32768;
        float acc[8] = {0,0,0,0,0,0,0,0};
        int n = tid;
        for (int d = 0; d < 128; ++d) {
            float wv = wti[d * 256 + n];
            #pragma unroll
            for (int r = 0; r < 8; ++r) acc[r] += xs[r * 128 + d] * wv;
        }
        float bv = lb[i * 256 + n];
        #pragma unroll
        for (int r = 0; r < 8; ++r) {
            float th = acc[r] + bv + tphi;
            int idx = ((int)rintf(th * SCALE_F)) & 4095;
            float ang = (float)idx * STEP_F;
            csh[r * 256 + n] = __cosf(ang);
            snh[r * 256 + n] = __sinf(ang);
        }
        __syncthreads();
        // phase 2: o[r][d] = cs . Wr[d] + sn . Wi[d] ; x += silu(o)
        int d2 = tid & 127, h = tid >> 7;
        const float* wri = wrt + i * 32768;
        const float* wii = wit + i * 32768;
        float a2[8] = {0,0,0,0,0,0,0,0};
        int n0 = h * 128;
        for (int nn = 0; nn < 128; ++nn) {
            float rv = wri[(n0 + nn) * 128 + d2];
            float iv = wii[(n0 + nn) * 128 + d2];
            #pragma unroll
            for (int r = 0; r < 8; ++r)
                a2[r] += csh[r * 256 + n0 + nn] * rv + snh[r * 256 + n0 + nn] * iv;
        }
        if (h) {
            #pragma unroll
            for (int r = 0; r < 8; ++r) part[r * 128 + d2] = a2[r];
        }
        __syncthreads();
        if (!h) {
            #pragma unroll
            for (int r = 0; r < 8; ++r) {
                float o = a2[r] + part[r * 128 + d2];
                float sg = 1.0f / (1.0f + __expf(-o));
                xs[r * 128 + d2] += o * sg;
            }
        }
        __syncthreads();
    }
    float4 xv = ((float4*)xs)[tid];
    unsigned int lo = ((unsigned)f2bf(xv.y) << 16) | f2bf(xv.x);
    unsigned int hi = ((unsigned)f2bf(xv.w) << 16) | f2bf(xv.z);
    ((uint2*)(X2bf + t * 1024))[tid] = make_uint2(lo, hi);
}

// ---------------------------------------------------------------------------
// logits GEMM: C(2048 x 50257) = X2(2048x128,bf16) * out_w^T(bf16)
// M-tile 256, N-tile 256, 1024 threads = 16 waves (4x4), wave = 64x64
// ---------------------------------------------------------------------------
typedef short bhalf8 __attribute__((ext_vector_type(8)));
typedef float fx4    __attribute__((ext_vector_type(4)));

__global__ __launch_bounds__(1024) void gemm_kernel(
        const unsigned short* __restrict__ X2bf,
        const unsigned short* __restrict__ outw_bf,
        float* __restrict__ out) {
    __shared__ __align__(16) unsigned short Ash[32768];   // 64 KB, fragment-permuted
    int tid = threadIdx.x;
    int mt = blockIdx.x & 7;
    int nt = blockIdx.x >> 3;
    // stage A tile permuted into MFMA fragment order: slot = (msub*4+ks)*64+lane
    for (int s = tid; s < 4096; s += 1024) {
        int blk = s >> 6, ln = s & 63;
        int msub = blk >> 2, ks = blk & 3;
        int row = mt * 256 + msub * 16 + (ln & 15);
        int kel = ks * 32 + ((ln >> 4) << 3);
        ((int4*)Ash)[s] = *(const int4*)(X2bf + row * 128 + kel);
    }
    __syncthreads();
    int lane = tid & 63, wave = tid >> 6;
    int wm = wave >> 2, wn = wave & 3;
    int ln15 = lane & 15, lq = lane >> 4;
    fx4 acc[4][4] = {};
    const bhalf8* Af = (const bhalf8*)Ash;
    for (int ks = 0; ks < 4; ++ks) {
        bhalf8 a0 = Af[((wm * 4 + 0) * 4 + ks) * 64 + lane];
        bhalf8 a1 = Af[((wm * 4 + 1) * 4 + ks) * 64 + lane];
        bhalf8 a2 = Af[((wm * 4 + 2) * 4 + ks) * 64 + lane];
        bhalf8 a3 = Af[((wm * 4 + 3) * 4 + ks) * 64 + lane];
        #pragma unroll
        for (int j = 0; j < 4; ++j) {
            int v = nt * 256 + wn * 64 + j * 16 + ln15;
            bhalf8 bfr = {};
            if (v < VOC)
                bfr = *(const bhalf8*)(outw_bf + v * 128 + ks * 32 + lq * 8);
            acc[0][j] = __builtin_amdgcn_mfma_f32_16x16x32_bf16(a0, bfr, acc[0][j], 0, 0, 0);
            acc[1][j] = __builtin_amdgcn_mfma_f32_16x16x32_bf16(a1, bfr, acc[1][j], 0, 0, 0);
            acc[2][j] = __builtin_amdgcn_mfma_f32_16x16x32_bf16(a2, bfr, acc[2][j], 0, 0, 0);
            acc[3][j] = __builtin_amdgcn_mfma_f32_16x16x32_bf16(a3, bfr, acc[3][j], 0, 0, 0);
        }
    }
    // store: C layout col=lane&15, row=(lane>>4)*4+reg ; out[b][t][v]
    #pragma unroll
    for (int i = 0; i < 4; ++i) {
        #pragma unroll
        for (int j = 0; j < 4; ++j) {
            int v = nt * 256 + wn * 64 + j * 16 + ln15;
            if (v < VOC) {
                int rbase = mt * 256 + wm * 64 + i * 16 + lq * 4;
                int tt = rbase >> 3;               // same t for all 4 regs
                int b0 = rbase & 7;
                size_t rowoff = (size_t)tt * VOC + v;
                #pragma unroll
                for (int rg = 0; rg < 4; ++rg) {
                    out[(size_t)(b0 + rg) * (SEQ * (size_t)VOC) + rowoff] = acc[i][j][rg];
                }
            }
        }
    }
}

// ---------------------------------------------------------------------------
extern "C" void kernel_launch(void* const* d_in, const int* in_sizes, int n_in,
                              void* d_out, int out_size, void* d_ws, size_t ws_size,
                              hipStream_t stream) {
    const int*   ids  = (const int*)d_in[0];
    const float* emb  = (const float*)d_in[1];
    const float* W    = (const float*)d_in[2];
    const float* lb   = (const float*)d_in[3];
    const float* Wr   = (const float*)d_in[4];
    const float* Wi   = (const float*)d_in[5];
    const float* outw = (const float*)d_in[6];
    float* out = (float*)d_out;
    char* ws = (char*)d_ws;

    unsigned short* outw_bf = (unsigned short*)ws;            // 12,865,792 B
    float* wt    = (float*)(ws + 12865792);                   // 262,144 B
    float* wrt   = wt + 65536;                                // 262,144 B
    float* wit   = wrt + 65536;                               // 262,144 B
    float* w_arr = wit + 65536;                               // 1,048,576 B
    float* b_arr = w_arr + 262144;                            // 1,048,576 B
    float* X0    = b_arr + 262144;                            // 1,048,576 B
    unsigned short* X2bf = (unsigned short*)(X0 + 262144);    // 524,288 B

    prep_kernel<<<8075, 256, 0, stream>>>(emb, ids, W, Wr, Wi, outw,
                                          outw_bf, wt, wrt, wit, w_arr, b_arr);
    recur_kernel<<<8, 128, 0, stream>>>(w_arr, b_arr, X0, out);
    layers_kernel<<<256, 256, 0, stream>>>(X0, wt, wrt, wit, lb, X2bf);
    gemm_kernel<<<8 * 197, 1024, 0, stream>>>(X2bf, outw_bf, out);
}